// Round 1
// baseline (686.191 us; speedup 1.0000x reference)
//
#include <hip/hip_runtime.h>

// Guided filter, fully fused: one kernel, zero workspace.
// Shapes: (16,3,512,512) fp32. RADIUS=8 -> 17x17 box windows, zero-padded,
// divided by analytic valid-pixel count N.
//
// Per block: 32x32 output tile of one plane.
//   Stage 1: load 64x64 halo region of I,p into LDS (zeros outside image).
//   Stage 2: horizontal 17-sums of {I, p, I*p, I*I} -> h arrays [64 rows][48 cols]
//   Stage 3: vertical 17-sums -> means -> a,b on 48x48 (zero outside image)
//   Stage 4: horizontal 17-sums of a,b -> [48][32]
//   Stage 5: vertical 17-sums -> mean_a, mean_b -> q = mean_a*I + mean_b
// All sliding-window passes in LDS; strides padded odd (65/49/33) to avoid
// bank conflicts on row-indexed (column-direction) access.

#define RAD  8
#define H    512
#define W    512
#define TILE 32
#define REG  64   // TILE + 4*RAD
#define CTR  48   // TILE + 2*RAD
#define EPS  0.01f

#define LS_I  65  // stride for 64-wide region arrays
#define LS_H  49  // stride for 48-wide h arrays
#define LS_A  33  // stride for 32-wide ha/hb arrays

__global__ __launch_bounds__(512)
void guided_filter_kernel(const float* __restrict__ Ig,
                          const float* __restrict__ Pg,
                          float* __restrict__ out)
{
    __shared__ float I_s[REG * LS_I];
    __shared__ float p_s[REG * LS_I];
    __shared__ float hI [REG * LS_H];
    __shared__ float hp [REG * LS_H];
    __shared__ float hIp[REG * LS_H];
    __shared__ float hII[REG * LS_H];
    __shared__ float a_s[CTR * LS_H];
    __shared__ float b_s[CTR * LS_H];
    __shared__ float ha [CTR * LS_A];
    __shared__ float hb [CTR * LS_A];

    const int tid   = threadIdx.x;
    const int plane = blockIdx.z;
    const int x0 = blockIdx.x * TILE - 2 * RAD;   // region origin (can be <0)
    const int y0 = blockIdx.y * TILE - 2 * RAD;
    const float* Ip_base = Ig + (size_t)plane * H * W;
    const float* Pp_base = Pg + (size_t)plane * H * W;

    // ---- Stage 1: stage 64x64 region, zero outside image ----
    for (int idx = tid; idx < REG * REG; idx += 512) {
        int ry = idx >> 6, rx = idx & 63;
        int gy = y0 + ry, gx = x0 + rx;
        bool v = ((unsigned)gy < (unsigned)H) && ((unsigned)gx < (unsigned)W);
        float iv = v ? Ip_base[gy * W + gx] : 0.f;
        float pv = v ? Pp_base[gy * W + gx] : 0.f;
        I_s[ry * LS_I + rx] = iv;
        p_s[ry * LS_I + rx] = pv;
    }
    __syncthreads();

    // ---- Stage 2: horizontal sums of I, p, I*p, I*I ----
    // 64 rows x 4 quantities x 2 half-rows = 512 tasks. q is wave-uniform.
    {
        int row  = tid & 63;
        int qh   = tid >> 6;      // 0..7
        int q    = qh & 3;
        int half = qh >> 2;       // 0 or 1
        int cx0  = half * 24;     // outputs [cx0, cx0+24)
        const float* Ir = &I_s[row * LS_I];
        const float* pr = &p_s[row * LS_I];
        float* dst = (q == 0) ? hI : (q == 1) ? hp : (q == 2) ? hIp : hII;
        auto val = [&](int x) -> float {
            float a = Ir[x];
            if (q == 0) return a;
            float b = pr[x];
            if (q == 1) return b;
            if (q == 2) return a * b;
            return a * a;
        };
        float s = 0.f;
        for (int j = 0; j < 17; ++j) s += val(cx0 + j);
        for (int c = cx0;;) {
            dst[row * LS_H + c] = s;
            ++c;
            if (c >= cx0 + 24) break;
            s += val(c + 16) - val(c - 1);
        }
    }
    __syncthreads();

    // ---- Stage 3: vertical sums -> a, b on 48x48 (halo for second filter) ----
    // 48 cols x 8 y-chunks of 6 rows = 384 tasks.
    if (tid < 384) {
        int cx    = tid % 48;
        int chunk = tid / 48;     // 0..7
        int cy0   = chunk * 6;
        float sI = 0.f, sp = 0.f, sIp = 0.f, sII = 0.f;
        for (int j = 0; j < 17; ++j) {
            int rr = (cy0 + j) * LS_H + cx;
            sI += hI[rr]; sp += hp[rr]; sIp += hIp[rr]; sII += hII[rr];
        }
        for (int cy = cy0;;) {
            int gy = y0 + RAD + cy;
            int gx = x0 + RAD + cx;
            float av = 0.f, bv = 0.f;
            if (((unsigned)gy < (unsigned)H) && ((unsigned)gx < (unsigned)W)) {
                int nx = min(gx + RAD, W - 1) - max(gx - RAD, 0) + 1;
                int ny = min(gy + RAD, H - 1) - max(gy - RAD, 0) + 1;
                float invN = 1.f / (float)(nx * ny);
                float mI  = sI * invN,  mp  = sp * invN;
                float mIp = sIp * invN, mII = sII * invN;
                float cov = mIp - mI * mp;
                float var = mII - mI * mI;
                av = cov / (var + EPS);
                bv = mp - av * mI;
            }
            a_s[cy * LS_H + cx] = av;
            b_s[cy * LS_H + cx] = bv;
            ++cy;
            if (cy >= cy0 + 6) break;
            int rA = (cy + 16) * LS_H + cx;
            int rS = (cy - 1) * LS_H + cx;
            sI  += hI [rA] - hI [rS];
            sp  += hp [rA] - hp [rS];
            sIp += hIp[rA] - hIp[rS];
            sII += hII[rA] - hII[rS];
        }
    }
    __syncthreads();

    // ---- Stage 4: horizontal sums of a, b -> [48][32] ----
    // 48 rows x 2 quantities x 2 halves = 192 tasks.
    if (tid < 192) {
        int cy   = tid % 48;
        int rest = tid / 48;      // 0..3
        int qq   = rest & 1;
        int half = rest >> 1;
        int ox0  = half * 16;
        const float* rowp = (qq ? b_s : a_s) + cy * LS_H;
        float* dst = qq ? hb : ha;
        float s = 0.f;
        for (int j = 0; j < 17; ++j) s += rowp[ox0 + j];
        for (int ox = ox0;;) {
            dst[cy * LS_A + ox] = s;
            ++ox;
            if (ox >= ox0 + 16) break;
            s += rowp[ox + 16] - rowp[ox - 1];
        }
    }
    __syncthreads();

    // ---- Stage 5: vertical sums -> q ----
    for (int idx = tid; idx < TILE * TILE; idx += 512) {
        int oy = idx >> 5, ox = idx & 31;
        float sa = 0.f, sb = 0.f;
        for (int j = 0; j < 17; ++j) {
            sa += ha[(oy + j) * LS_A + ox];
            sb += hb[(oy + j) * LS_A + ox];
        }
        int gy = y0 + 2 * RAD + oy;   // = blockIdx.y*TILE + oy, always in-bounds
        int gx = x0 + 2 * RAD + ox;
        int nx = min(gx + RAD, W - 1) - max(gx - RAD, 0) + 1;
        int ny = min(gy + RAD, H - 1) - max(gy - RAD, 0) + 1;
        float invN = 1.f / (float)(nx * ny);
        float iv = I_s[(oy + 2 * RAD) * LS_I + (ox + 2 * RAD)];
        out[(size_t)plane * H * W + (size_t)gy * W + gx] = (sa * invN) * iv + sb * invN;
    }
}

extern "C" void kernel_launch(void* const* d_in, const int* in_sizes, int n_in,
                              void* d_out, int out_size, void* d_ws, size_t ws_size,
                              hipStream_t stream) {
    const float* I = (const float*)d_in[0];
    const float* P = (const float*)d_in[1];
    float* out = (float*)d_out;
    int planes = in_sizes[0] / (H * W);   // 16*3 = 48
    dim3 grid(W / TILE, H / TILE, planes);
    guided_filter_kernel<<<grid, dim3(512), 0, stream>>>(I, P, out);
}

// Round 3
// 257.867 us; speedup vs baseline: 2.6610x; 2.6610x over previous
//
#include <hip/hip_runtime.h>

// Guided filter fused kernel, round 2 (resubmit after infra failure).
// (16,3,512,512) fp32, r=8 (17x17 box, zero 'same' padding, analytic N).
//
// Per block: 32x32 output tile, region 64x64, center (a,b) 48x48.
// LDS plan (exactly 80 KiB -> 2 blocks/CU):
//   F2 : float2(I,p)[64][64], column-rotated (phys c = (c+4r)&63) -> 32768 B
//        after stage 2 the same space holds AB (48x49 float2) + HAB (48x33 float2)
//   H4 : float4(sI,sp,sIp,sII)[64][48] horizontal window sums       -> 49152 B
// Stages (512 threads):
//   S1: global->LDS region load (float4 fast path for interior blocks)
//   S2: per-(row,eighth) register sliding 17-sums of (I,p,Ip,II) -> H4 (b128)
//   S3: per-(col,chunk6) vertical sliding float4 sums -> a,b -> AB (b64)
//   S4: per-(row,eighth4) horizontal sliding sums of (a,b) -> HAB
//   S5: per-(col,chunk2) vertical sliding sums -> q, I re-read from global (L2-hot)

#define RAD  8
#define H    512
#define W    512
#define TILE 32
#define EPS  0.01f

__global__ __launch_bounds__(512, 4)
void guided_filter_kernel(const float* __restrict__ Ig,
                          const float* __restrict__ Pg,
                          float* __restrict__ out)
{
    __shared__ __align__(16) char smem_lo[32768];
    __shared__ float4 H4[64 * 48];

    float2* F2  = (float2*)smem_lo;              // 64 x 64 (rotated cols)
    float2* AB  = (float2*)smem_lo;              // 48 x stride 49
    float2* HAB = (float2*)(smem_lo + 18816);    // 48 x stride 33

    const int tid   = threadIdx.x;
    const int plane = blockIdx.z;
    const int x0 = blockIdx.x * TILE - 2 * RAD;
    const int y0 = blockIdx.y * TILE - 2 * RAD;
    const float* Ib = Ig + (size_t)plane * (H * W);
    const float* Pb = Pg + (size_t)plane * (H * W);
    float* Ob = out + (size_t)plane * (H * W);

    // ---------------- Stage 1: region -> F2 ----------------
    const bool interior = (x0 >= 0) && (y0 >= 0) && (x0 + 64 <= W) && (y0 + 64 <= H);
    if (interior) {
        #pragma unroll
        for (int it = 0; it < 2; ++it) {
            int idx = it * 512 + tid;
            int ry = idx >> 4, f4 = idx & 15;
            const float* ip = Ib + (y0 + ry) * W + x0 + 4 * f4;
            const float* pp = Pb + (y0 + ry) * W + x0 + 4 * f4;
            float4 iv = *(const float4*)ip;
            float4 pv = *(const float4*)pp;
            int pc = (4 * f4 + 4 * ry) & 63;
            float2* dst = &F2[ry * 64 + pc];
            dst[0] = make_float2(iv.x, pv.x);
            dst[1] = make_float2(iv.y, pv.y);
            dst[2] = make_float2(iv.z, pv.z);
            dst[3] = make_float2(iv.w, pv.w);
        }
    } else {
        #pragma unroll
        for (int it = 0; it < 2; ++it) {
            int idx = it * 512 + tid;
            int ry = idx >> 4, f4 = idx & 15;
            int gy = y0 + ry;
            int pc = (4 * f4 + 4 * ry) & 63;
            float2* dst = &F2[ry * 64 + pc];
            #pragma unroll
            for (int k = 0; k < 4; ++k) {
                int gx = x0 + 4 * f4 + k;
                bool v = ((unsigned)gy < (unsigned)H) && ((unsigned)gx < (unsigned)W);
                float a = v ? Ib[gy * W + gx] : 0.f;
                float b = v ? Pb[gy * W + gx] : 0.f;
                dst[k] = make_float2(a, b);
            }
        }
    }
    __syncthreads();

    // ---------------- Stage 2: horizontal 17-sums -> H4 ----------------
    {
        int r = tid >> 3, e = tid & 7;
        const float2* Frow = &F2[r * 64];
        const int rot = 4 * r;
        const int c0 = 6 * e;
        float4 S = make_float4(0.f, 0.f, 0.f, 0.f);
        #pragma unroll
        for (int j = 0; j < 17; ++j) {
            float2 v = Frow[(c0 + j + rot) & 63];
            S.x += v.x; S.y += v.y; S.z += v.x * v.y; S.w += v.x * v.x;
        }
        #pragma unroll
        for (int k = 0; k < 6; ++k) {
            H4[r * 48 + c0 + k] = S;
            if (k < 5) {
                float2 va = Frow[(c0 + k + 17 + rot) & 63];
                float2 vs = Frow[(c0 + k + rot) & 63];
                S.x += va.x - vs.x;
                S.y += va.y - vs.y;
                S.z += va.x * va.y - vs.x * vs.y;
                S.w += va.x * va.x - vs.x * vs.x;
            }
        }
    }
    __syncthreads();

    // ---------------- Stage 3: vertical 17-sums -> a,b -> AB ----------------
    // (AB aliases F2's space; safe: barrier above ends all F2 reads)
    if (tid < 384) {
        int col   = tid % 48;
        int chunk = tid / 48;      // 0..7
        int cy0   = chunk * 6;
        float4 S = make_float4(0.f, 0.f, 0.f, 0.f);
        #pragma unroll
        for (int j = 0; j < 17; ++j) {
            float4 v = H4[(cy0 + j) * 48 + col];
            S.x += v.x; S.y += v.y; S.z += v.z; S.w += v.w;
        }
        int gx = x0 + RAD + col;
        int nx = min(gx + RAD, W - 1) - max(gx - RAD, 0) + 1;
        #pragma unroll
        for (int k = 0; k < 6; ++k) {
            int cy = cy0 + k;
            int gy = y0 + RAD + cy;
            float a = 0.f, b = 0.f;
            if (((unsigned)gy < (unsigned)H) && ((unsigned)gx < (unsigned)W)) {
                int ny = min(gy + RAD, H - 1) - max(gy - RAD, 0) + 1;
                float invN = 1.f / (float)(nx * ny);
                float mI = S.x * invN, mp = S.y * invN;
                float cov = S.z * invN - mI * mp;
                float var = S.w * invN - mI * mI;
                a = cov / (var + EPS);
                b = mp - a * mI;
            }
            AB[cy * 49 + col] = make_float2(a, b);
            if (k < 5) {
                float4 va = H4[(cy + 17) * 48 + col];
                float4 vs = H4[cy * 48 + col];
                S.x += va.x - vs.x; S.y += va.y - vs.y;
                S.z += va.z - vs.z; S.w += va.w - vs.w;
            }
        }
    }
    __syncthreads();

    // ---------------- Stage 4: horizontal 17-sums of a,b -> HAB ----------------
    if (tid < 384) {
        int r = tid % 48;
        int e = tid / 48;          // 0..7, 4 output cols each
        const float2* row = &AB[r * 49];
        const int c0 = 4 * e;
        float2 S = make_float2(0.f, 0.f);
        #pragma unroll
        for (int j = 0; j < 17; ++j) {
            float2 v = row[c0 + j];
            S.x += v.x; S.y += v.y;
        }
        #pragma unroll
        for (int k = 0; k < 4; ++k) {
            HAB[r * 33 + c0 + k] = S;
            if (k < 3) {
                float2 va = row[c0 + k + 17];
                float2 vs = row[c0 + k];
                S.x += va.x - vs.x; S.y += va.y - vs.y;
            }
        }
    }
    __syncthreads();

    // ---------------- Stage 5: vertical 17-sums -> q ----------------
    {
        int col   = tid & 31;
        int chunk = tid >> 5;      // 0..15, 2 output rows each
        int oy0   = chunk * 2;
        float2 S = make_float2(0.f, 0.f);
        #pragma unroll
        for (int j = 0; j < 17; ++j) {
            float2 v = HAB[(oy0 + j) * 33 + col];
            S.x += v.x; S.y += v.y;
        }
        int gx = x0 + 2 * RAD + col;
        int nx = min(gx + RAD, W - 1) - max(gx - RAD, 0) + 1;
        #pragma unroll
        for (int k = 0; k < 2; ++k) {
            int oy = oy0 + k;
            int gy = y0 + 2 * RAD + oy;
            int ny = min(gy + RAD, H - 1) - max(gy - RAD, 0) + 1;
            float invN = 1.f / (float)(nx * ny);
            float iv = Ib[gy * W + gx];
            Ob[gy * W + gx] = S.x * invN * iv + S.y * invN;
            if (k < 1) {
                float2 va = HAB[(oy + 17) * 33 + col];
                float2 vs = HAB[oy * 33 + col];
                S.x += va.x - vs.x; S.y += va.y - vs.y;
            }
        }
    }
}

extern "C" void kernel_launch(void* const* d_in, const int* in_sizes, int n_in,
                              void* d_out, int out_size, void* d_ws, size_t ws_size,
                              hipStream_t stream) {
    const float* I = (const float*)d_in[0];
    const float* P = (const float*)d_in[1];
    float* out = (float*)d_out;
    int planes = in_sizes[0] / (H * W);   // 48
    dim3 grid(W / TILE, H / TILE, planes);
    guided_filter_kernel<<<grid, dim3(512), 0, stream>>>(I, P, out);
}

// Round 4
// 248.062 us; speedup vs baseline: 2.7662x; 1.0395x over previous
//
#include <hip/hip_runtime.h>

// Guided filter fused kernel, round 4: bank-conflict-free LDS swizzles.
// (16,3,512,512) fp32, r=8 (17x17 box, zero 'same' padding, analytic N).
//
// Per block: 32x32 output tile, region 64x64, center (a,b) 48x48.
// LDS = exactly 80 KiB -> 2 blocks/CU:
//   F4 : region (I,p) as float4 granules [64 rows][32 granules], swizzled
//        phys_granule = g ^ (row&7), halves swapped iff (row&1). 32768 B.
//        After stage 2, same space holds AB (48 x stride 50 float2, rows
//        16B-aligned) and HAB (48 x stride 33 float2).
//   H4 : (sI,sp,sIp,sII) float4 [64][48], phys_col = col ^ (row&7). 49152 B.
// All swizzles verified by bank arithmetic to give minimal LDS cycles
// (row strides alone are bank-period multiples -> the XOR spreads rows).

#define RAD  8
#define H    512
#define W    512
#define TILE 32
#define EPS  0.01f

__global__ __launch_bounds__(512, 4)
void guided_filter_kernel(const float* __restrict__ Ig,
                          const float* __restrict__ Pg,
                          float* __restrict__ out)
{
    __shared__ __align__(16) float4 F4[64 * 32];   // 32768 B
    __shared__ __align__(16) float4 H4[64 * 48];   // 49152 B

    float2* F2p = (float2*)F4;
    float2* AB  = (float2*)F4;                 // 48 rows x stride 50 (19200 B)
    float2* HAB = (float2*)F4 + 48 * 50;       // 48 rows x stride 33 (12672 B)

    const int tid   = threadIdx.x;
    const int plane = blockIdx.z;
    const int x0 = blockIdx.x * TILE - 2 * RAD;
    const int y0 = blockIdx.y * TILE - 2 * RAD;
    const float* Ib = Ig + (size_t)plane * (H * W);
    const float* Pb = Pg + (size_t)plane * (H * W);
    float* Ob = out + (size_t)plane * (H * W);

    // ---------------- Stage 1: region -> F4 (swizzled) ----------------
    const bool interior = (x0 >= 0) && (y0 >= 0) && (x0 + 64 <= W) && (y0 + 64 <= H);
    if (interior) {
        #pragma unroll
        for (int it = 0; it < 2; ++it) {
            int idx = it * 512 + tid;
            int ry = idx >> 4, f4 = idx & 15;
            int rl = ry & 7, pf = ry & 1;
            const float* ip = Ib + (y0 + ry) * W + x0 + 4 * f4;
            const float* pp = Pb + (y0 + ry) * W + x0 + 4 * f4;
            float4 iv = *(const float4*)ip;
            float4 pv = *(const float4*)pp;
            float2 e0 = make_float2(iv.x, pv.x), e1 = make_float2(iv.y, pv.y);
            float2 e2 = make_float2(iv.z, pv.z), e3 = make_float2(iv.w, pv.w);
            float2 a0 = pf ? e1 : e0, a1 = pf ? e0 : e1;
            float2 b0 = pf ? e3 : e2, b1 = pf ? e2 : e3;
            float4* Fr = &F4[ry * 32];
            Fr[(2 * f4) ^ rl]     = make_float4(a0.x, a0.y, a1.x, a1.y);
            Fr[(2 * f4 + 1) ^ rl] = make_float4(b0.x, b0.y, b1.x, b1.y);
        }
    } else {
        #pragma unroll
        for (int it = 0; it < 2; ++it) {
            int idx = it * 512 + tid;
            int ry = idx >> 4, f4 = idx & 15;
            int rl = ry & 7, pf = ry & 1;
            int gy = y0 + ry;
            float2 el[4];
            #pragma unroll
            for (int k = 0; k < 4; ++k) {
                int gx = x0 + 4 * f4 + k;
                bool v = ((unsigned)gy < (unsigned)H) && ((unsigned)gx < (unsigned)W);
                el[k].x = v ? Ib[gy * W + gx] : 0.f;
                el[k].y = v ? Pb[gy * W + gx] : 0.f;
            }
            float2 a0 = pf ? el[1] : el[0], a1 = pf ? el[0] : el[1];
            float2 b0 = pf ? el[3] : el[2], b1 = pf ? el[2] : el[3];
            float4* Fr = &F4[ry * 32];
            Fr[(2 * f4) ^ rl]     = make_float4(a0.x, a0.y, a1.x, a1.y);
            Fr[(2 * f4 + 1) ^ rl] = make_float4(b0.x, b0.y, b1.x, b1.y);
        }
    }
    __syncthreads();

    // ---------------- Stage 2: horizontal 17-sums -> H4 ----------------
    {
        const int r  = tid >> 3, e = tid & 7;
        const int rl = r & 7, pf = r & 1;
        const int c0 = 6 * e;
        const float4* Fr = &F4[r * 32];
        const float2* Er = &F2p[r * 64];
        float4 S = make_float4(0.f, 0.f, 0.f, 0.f);
        const int g0 = 3 * e;
        #pragma unroll
        for (int m = 0; m < 8; ++m) {   // elements c0 .. c0+15 (order-independent sum)
            float4 g = Fr[(g0 + m) ^ rl];
            S.x += g.x + g.z;
            S.y += g.y + g.w;
            S.z += g.x * g.y + g.z * g.w;
            S.w += g.x * g.x + g.z * g.z;
        }
        {
            int c = c0 + 16;            // even -> within-granule slot = pf
            float2 v = Er[(((c >> 1) ^ rl) << 1) | pf];
            S.x += v.x; S.y += v.y; S.z += v.x * v.y; S.w += v.x * v.x;
        }
        #pragma unroll
        for (int k = 0; k < 6; ++k) {
            H4[r * 48 + ((c0 + k) ^ rl)] = S;
            if (k < 5) {
                int ca = c0 + k + 17, cs = c0 + k;
                float2 va = Er[(((ca >> 1) ^ rl) << 1) | ((ca & 1) ^ pf)];
                float2 vs = Er[(((cs >> 1) ^ rl) << 1) | ((cs & 1) ^ pf)];
                S.x += va.x - vs.x;
                S.y += va.y - vs.y;
                S.z += va.x * va.y - vs.x * vs.y;
                S.w += va.x * va.x - vs.x * vs.x;
            }
        }
    }
    __syncthreads();

    // ---------------- Stage 3: vertical 17-sums -> a,b -> AB ----------------
    if (tid < 384) {
        const int col = tid % 48, chunk = tid / 48;
        const int cy0 = chunk * 6;
        float4 S = make_float4(0.f, 0.f, 0.f, 0.f);
        #pragma unroll
        for (int j = 0; j < 17; ++j) {
            int row = cy0 + j;
            float4 v = H4[row * 48 + (col ^ (row & 7))];
            S.x += v.x; S.y += v.y; S.z += v.z; S.w += v.w;
        }
        int gx = x0 + RAD + col;
        int nx = min(gx + RAD, W - 1) - max(gx - RAD, 0) + 1;
        #pragma unroll
        for (int k = 0; k < 6; ++k) {
            int cy = cy0 + k;
            int gy = y0 + RAD + cy;
            float a = 0.f, b = 0.f;
            if (((unsigned)gy < (unsigned)H) && ((unsigned)gx < (unsigned)W)) {
                int ny = min(gy + RAD, H - 1) - max(gy - RAD, 0) + 1;
                float invN = __builtin_amdgcn_rcpf((float)(nx * ny));
                float mI = S.x * invN, mp = S.y * invN;
                float cov = S.z * invN - mI * mp;
                float var = S.w * invN - mI * mI;
                a = cov * __builtin_amdgcn_rcpf(var + EPS);
                b = mp - a * mI;
            }
            AB[cy * 50 + col] = make_float2(a, b);
            if (k < 5) {
                int ra = cy + 17, rs = cy;
                float4 va = H4[ra * 48 + (col ^ (ra & 7))];
                float4 vs = H4[rs * 48 + (col ^ (rs & 7))];
                S.x += va.x - vs.x; S.y += va.y - vs.y;
                S.z += va.z - vs.z; S.w += va.w - vs.w;
            }
        }
    }
    __syncthreads();

    // ---------------- Stage 4: horizontal 17-sums of a,b -> HAB ----------------
    if (tid < 384) {
        const int r = tid % 48, e = tid / 48;   // e in 0..7, 4 output cols each
        const int c0 = 4 * e;
        const float2* row  = &AB[r * 50];
        const float4* rowg = (const float4*)row;   // rows 16B-aligned (stride 400B)
        float2 S = make_float2(0.f, 0.f);
        #pragma unroll
        for (int m = 0; m < 8; ++m) {           // elements c0 .. c0+15
            float4 g = rowg[2 * e + m];
            S.x += g.x + g.z;
            S.y += g.y + g.w;
        }
        {
            float2 v = row[c0 + 16];
            S.x += v.x; S.y += v.y;
        }
        #pragma unroll
        for (int k = 0; k < 4; ++k) {
            HAB[r * 33 + c0 + k] = S;
            if (k < 3) {
                float2 va = row[c0 + k + 17];
                float2 vs = row[c0 + k];
                S.x += va.x - vs.x; S.y += va.y - vs.y;
            }
        }
    }
    __syncthreads();

    // ---------------- Stage 5: vertical 17-sums -> q ----------------
    {
        const int col = tid & 31, chunk = tid >> 5;   // 16 chunks x 2 rows
        const int oy0 = chunk * 2;
        float2 S = make_float2(0.f, 0.f);
        #pragma unroll
        for (int j = 0; j < 17; ++j) {
            float2 v = HAB[(oy0 + j) * 33 + col];
            S.x += v.x; S.y += v.y;
        }
        int gx = x0 + 2 * RAD + col;
        int nx = min(gx + RAD, W - 1) - max(gx - RAD, 0) + 1;
        #pragma unroll
        for (int k = 0; k < 2; ++k) {
            int oy = oy0 + k;
            int gy = y0 + 2 * RAD + oy;
            int ny = min(gy + RAD, H - 1) - max(gy - RAD, 0) + 1;
            float invN = __builtin_amdgcn_rcpf((float)(nx * ny));
            float iv = Ib[gy * W + gx];
            Ob[gy * W + gx] = S.x * invN * iv + S.y * invN;
            if (k < 1) {
                float2 va = HAB[(oy + 17) * 33 + col];
                float2 vs = HAB[oy * 33 + col];
                S.x += va.x - vs.x; S.y += va.y - vs.y;
            }
        }
    }
}

extern "C" void kernel_launch(void* const* d_in, const int* in_sizes, int n_in,
                              void* d_out, int out_size, void* d_ws, size_t ws_size,
                              hipStream_t stream) {
    const float* I = (const float*)d_in[0];
    const float* P = (const float*)d_in[1];
    float* out = (float*)d_out;
    int planes = in_sizes[0] / (H * W);   // 48
    dim3 grid(W / TILE, H / TILE, planes);
    guided_filter_kernel<<<grid, dim3(512), 0, stream>>>(I, P, out);
}